// Round 10
// baseline (315.476 us; speedup 1.0000x reference)
//
#include <hip/hip_runtime.h>
#include <math.h>

#define N_NODES 100000
#define N_EDGES 1600000
#define F_IN    16
#define H_DIM   32
#define B_GRAPHS 256

#define BSHIFT  7
#define BSIZE   128                                   // nodes per bucket
#define NBUCKET ((N_NODES + BSIZE - 1) / BSIZE)       // 782
#define EPB     8192                                  // edges per chunk block
#define NCHUNK  ((N_EDGES + EPB - 1) / EPB)           // 196
#define CAPB    2560                                  // fixed bucket stride (mean 2048, +11 sigma)
#define CSTRIDE 2944                                  // csr entries reserved per bucket (2560+384)
#define TPAD    (NBUCKET * CSTRIDE)
#define NPB     16                                    // nodes per layer block
#define LAYER_BLOCKS (N_NODES / NPB)                  // 6250

typedef int v4i __attribute__((ext_vector_type(4)));  // nontemporal-load-able int4

// ---------------------------------------------------------------------------
__device__ inline float bf_lo(unsigned u) { return __uint_as_float(u << 16); }
__device__ inline float bf_hi(unsigned u) { return __uint_as_float(u & 0xffff0000u); }
__device__ inline unsigned pack_bf16x2(float a, float b) {
    unsigned ua = __float_as_uint(a), ub = __float_as_uint(b);
    ua += 0x7fffu + ((ua >> 16) & 1u);    // RNE
    ub += 0x7fffu + ((ub >> 16) & 1u);
    return (ua >> 16) | (ub & 0xffff0000u);
}

// ---------------------------------------------------------------------------
// bucket_cur[b] = b * CAPB  (fixed-stride bucket layout)
__global__ __launch_bounds__(256) void init_cur_kernel(int* __restrict__ bucket_cur) {
    int b = blockIdx.x * 256 + threadIdx.x;
    if (b < NBUCKET) bucket_cur[b] = b * CAPB;
}

// Pass B: per-block histogram -> claim per-bucket runs -> direct scattered
// writes (run-contiguous => low writeback amp). Record = src | dst_local<<20.
__global__ __launch_bounds__(256) void passB_kernel(const int* __restrict__ ei,
                                                    int* __restrict__ bucket_cur,
                                                    unsigned* __restrict__ rec_out) {
    __shared__ int hist[NBUCKET];
    __shared__ int gcur[NBUCKET];
    int t = threadIdx.x;
    for (int k = t; k < NBUCKET; k += 256) hist[k] = 0;
    __syncthreads();

    const int* dst = ei + N_EDGES;
    int base = blockIdx.x * EPB;
    int end  = base + EPB; if (end > N_EDGES) end = N_EDGES;

    for (int e = base + t; e < end; e += 256) atomicAdd(&hist[dst[e] >> BSHIFT], 1);
    __syncthreads();

    for (int k = t; k < NBUCKET; k += 256) {
        int h = hist[k];
        gcur[k] = h ? atomicAdd(&bucket_cur[k], h) : 0;
    }
    __syncthreads();

    for (int e = base + t; e < end; e += 256) {
        int d = dst[e], s = ei[e];
        int bk = d >> BSHIFT;
        int pos = atomicAdd(&gcur[bk], 1);
        rec_out[pos] = (unsigned)s | ((unsigned)(d & (BSIZE - 1)) << 20);
    }
}

// Per-bucket in-degree -> dinv
__global__ __launch_bounds__(256) void dinv_kernel(const unsigned* __restrict__ rec,
                                                   const int* __restrict__ bucket_end,
                                                   float* __restrict__ dinv) {
    __shared__ int cnt[BSIZE];
    int t = threadIdx.x, b = blockIdx.x;
    if (t < BSIZE) cnt[t] = 0;
    __syncthreads();
    int e1 = bucket_end[b];
    for (int e = b * CAPB + t; e < e1; e += 256)
        atomicAdd(&cnt[__builtin_nontemporal_load(&rec[e]) >> 20], 1);
    __syncthreads();
    int nd = (b << BSHIFT) + t;
    if (t < BSIZE && nd < N_NODES) dinv[nd] = rsqrtf((float)cnt[t] + 1.0f);
}

// Pass C: per-bucket node sort into padded interleaved CSR (entry=(src,coef)),
// rows padded to mult-of-4, dummy = own node w/ coef 0. Nodes are RANKED by
// padded length (bitonic, desc, valid-first) so co-waved rows have equal
// length; CSR storage allocated in rank order. Emits rank-space
// row_meta=(start,padded_len) and perm[rank]=node.
__global__ __launch_bounds__(256) void passC_kernel(const unsigned* __restrict__ rec,
                                                    const int* __restrict__ bucket_end,
                                                    const float* __restrict__ dinv,
                                                    int2* __restrict__ row_meta,
                                                    int* __restrict__ perm,
                                                    int2* __restrict__ csr) {
    __shared__ unsigned stage[CAPB];
    __shared__ int cnt[BSIZE];
    __shared__ unsigned key[BSIZE];
    __shared__ int pds[BSIZE];
    __shared__ int cur[BSIZE];
    __shared__ float sdv[BSIZE];
    int t = threadIdx.x, b = blockIdx.x;
    int node0 = b << BSHIFT;
    int e0 = b * CAPB;
    int n = bucket_end[b] - e0;
    int pbase = b * CSTRIDE;
    if (t < BSIZE) {
        cnt[t] = 0;
        int nd = node0 + t;
        sdv[t] = (nd < N_NODES) ? dinv[nd] : 0.f;
    }
    __syncthreads();
    for (int k = t; k < n; k += 256) {
        unsigned r = __builtin_nontemporal_load(&rec[e0 + k]);
        stage[k] = r;
        atomicAdd(&cnt[r >> 20], 1);
    }
    __syncthreads();

    // build sort keys: valid<<30 | padded_len<<16 | local_node
    if (t < BSIZE) {
        int pd = (cnt[t] + 3) & ~3;
        unsigned valid = (node0 + t < N_NODES) ? 1u : 0u;
        key[t] = (valid << 30) | ((unsigned)pd << 16) | (unsigned)t;
    }
    __syncthreads();
    // bitonic sort, descending
    for (unsigned kk = 2; kk <= BSIZE; kk <<= 1) {
        for (unsigned jj = kk >> 1; jj > 0; jj >>= 1) {
            if (t < BSIZE) {
                unsigned ixj = t ^ jj;
                if (ixj > (unsigned)t) {
                    unsigned a = key[t], c = key[ixj];
                    bool up = ((t & kk) == 0);        // descending in 'up' regions
                    if (up ? (a < c) : (a > c)) { key[t] = c; key[ixj] = a; }
                }
            }
            __syncthreads();
        }
    }

    // rank-order allocation: scan padded lengths over ranks
    int pd_r = 0;
    if (t < BSIZE) { pd_r = (int)((key[t] >> 16) & 0x3FFFu); pds[t] = pd_r; }
    __syncthreads();
    for (int off = 1; off < BSIZE; off <<= 1) {
        int v = (t < BSIZE && t >= off) ? pds[t - off] : 0;
        __syncthreads();
        if (t < BSIZE) pds[t] += v;
        __syncthreads();
    }
    if (t < BSIZE) {
        unsigned k = key[t];
        int ln = (int)(k & 0x7Fu);
        int startp = pbase + pds[t] - pd_r;
        cur[ln] = startp;
        if ((k >> 30) & 1u) {             // valid node
            int nd = node0 + ln;
            row_meta[node0 + t] = make_int2(startp, pd_r);
            perm[node0 + t]     = nd;
            for (int q = startp + cnt[ln]; q < startp + pd_r; ++q)
                csr[q] = make_int2(nd, 0);   // dummy: own node, coef 0
        }
    }
    __syncthreads();
    for (int k = t; k < n; k += 256) {
        unsigned r = stage[k];
        int dl = r >> 20;
        int s  = r & 0xFFFFF;
        int pos = atomicAdd(&cur[dl], 1);
        csr[pos] = make_int2(s, __float_as_int(dinv[s] * sdv[dl]));
    }
}

// ---------------------------------------------------------------------------
// GCN layer: rank-scheduled gather aggregation, 8-edge chunks + 4-edge tail,
// csr as nontemporal v4i loads; fused W + bias + tanh + bf16x2 pack.
template <int FIN, bool PACKED>
__global__ __launch_bounds__(256) void layer_kernel(
        const void* __restrict__ h_in_v,
        const int2* __restrict__ row_meta,   // rank space
        const int* __restrict__ perm,        // rank -> node
        const v4i* __restrict__ csr4,        // 2 edges per v4i
        const float* __restrict__ dinv,
        const float* __restrict__ W,         // [FIN][32]
        const float* __restrict__ bias,      // [32]
        unsigned* __restrict__ h_out) {
    constexpr int STR = FIN + 1;
    __shared__ float sW[FIN * H_DIM];
    __shared__ float sb[H_DIM];
    __shared__ float agg[NPB][STR];
    int t = threadIdx.x;
    for (int k = t; k < FIN * H_DIM; k += 256) sW[k] = W[k];
    if (t < H_DIM) sb[t] = bias[t];

    int nl = t >> 4, ln = t & 15;
    int ri = blockIdx.x * NPB + nl;
    int i = perm[ri];
    int2 m = row_meta[ri];
    float di = dinv[i], di2 = di * di;
    int q    = m.x >> 1;                // v4i index of row start (16B-aligned)
    int qend = (m.x + m.y) >> 1;

    if (PACKED) {
        const unsigned* hp = (const unsigned*)h_in_v;
        unsigned u = hp[i * 16 + ln];
        float acc0 = bf_lo(u) * di2, acc1 = bf_hi(u) * di2;
        for (; q + 4 <= qend; q += 4) {
            v4i a = __builtin_nontemporal_load(&csr4[q]);
            v4i b = __builtin_nontemporal_load(&csr4[q + 1]);
            v4i c = __builtin_nontemporal_load(&csr4[q + 2]);
            v4i d = __builtin_nontemporal_load(&csr4[q + 3]);
            unsigned v0 = hp[a.x * 16 + ln], v1 = hp[a.z * 16 + ln];
            unsigned v2 = hp[b.x * 16 + ln], v3 = hp[b.z * 16 + ln];
            unsigned v4 = hp[c.x * 16 + ln], v5 = hp[c.z * 16 + ln];
            unsigned v6 = hp[d.x * 16 + ln], v7 = hp[d.z * 16 + ln];
            float c0 = __int_as_float(a.y), c1 = __int_as_float(a.w);
            float c2 = __int_as_float(b.y), c3 = __int_as_float(b.w);
            float c4 = __int_as_float(c.y), c5 = __int_as_float(c.w);
            float c6 = __int_as_float(d.y), c7 = __int_as_float(d.w);
            acc0 += bf_lo(v0) * c0 + bf_lo(v1) * c1 + bf_lo(v2) * c2 + bf_lo(v3) * c3
                  + bf_lo(v4) * c4 + bf_lo(v5) * c5 + bf_lo(v6) * c6 + bf_lo(v7) * c7;
            acc1 += bf_hi(v0) * c0 + bf_hi(v1) * c1 + bf_hi(v2) * c2 + bf_hi(v3) * c3
                  + bf_hi(v4) * c4 + bf_hi(v5) * c5 + bf_hi(v6) * c6 + bf_hi(v7) * c7;
        }
        if (q < qend) {                  // exactly 2 v4is (4 edges)
            v4i a = __builtin_nontemporal_load(&csr4[q]);
            v4i b = __builtin_nontemporal_load(&csr4[q + 1]);
            unsigned v0 = hp[a.x * 16 + ln], v1 = hp[a.z * 16 + ln];
            unsigned v2 = hp[b.x * 16 + ln], v3 = hp[b.z * 16 + ln];
            float c0 = __int_as_float(a.y), c1 = __int_as_float(a.w);
            float c2 = __int_as_float(b.y), c3 = __int_as_float(b.w);
            acc0 += bf_lo(v0) * c0 + bf_lo(v1) * c1 + bf_lo(v2) * c2 + bf_lo(v3) * c3;
            acc1 += bf_hi(v0) * c0 + bf_hi(v1) * c1 + bf_hi(v2) * c2 + bf_hi(v3) * c3;
        }
        agg[nl][2 * ln]     = acc0;
        agg[nl][2 * ln + 1] = acc1;
    } else {
        const float* xf = (const float*)h_in_v;
        float acc = xf[i * F_IN + ln] * di2;
        for (; q + 4 <= qend; q += 4) {
            v4i a = __builtin_nontemporal_load(&csr4[q]);
            v4i b = __builtin_nontemporal_load(&csr4[q + 1]);
            v4i c = __builtin_nontemporal_load(&csr4[q + 2]);
            v4i d = __builtin_nontemporal_load(&csr4[q + 3]);
            float v0 = xf[a.x * F_IN + ln], v1 = xf[a.z * F_IN + ln];
            float v2 = xf[b.x * F_IN + ln], v3 = xf[b.z * F_IN + ln];
            float v4 = xf[c.x * F_IN + ln], v5 = xf[c.z * F_IN + ln];
            float v6 = xf[d.x * F_IN + ln], v7 = xf[d.z * F_IN + ln];
            acc += v0 * __int_as_float(a.y) + v1 * __int_as_float(a.w)
                 + v2 * __int_as_float(b.y) + v3 * __int_as_float(b.w)
                 + v4 * __int_as_float(c.y) + v5 * __int_as_float(c.w)
                 + v6 * __int_as_float(d.y) + v7 * __int_as_float(d.w);
        }
        if (q < qend) {
            v4i a = __builtin_nontemporal_load(&csr4[q]);
            v4i b = __builtin_nontemporal_load(&csr4[q + 1]);
            float v0 = xf[a.x * F_IN + ln], v1 = xf[a.z * F_IN + ln];
            float v2 = xf[b.x * F_IN + ln], v3 = xf[b.z * F_IN + ln];
            acc += v0 * __int_as_float(a.y) + v1 * __int_as_float(a.w)
                 + v2 * __int_as_float(b.y) + v3 * __int_as_float(b.w);
        }
        agg[nl][ln] = acc;
    }
    __syncthreads();

    // transform + bias + tanh + pack  (16 nodes x 16 feat-pairs)
    int j0 = 2 * ln;
    float o0 = sb[j0], o1 = sb[j0 + 1];
    const float* arow = &agg[nl][0];
#pragma unroll
    for (int k = 0; k < FIN; ++k) {
        float a = arow[k];
        o0 += a * sW[k * H_DIM + j0];
        o1 += a * sW[k * H_DIM + j0 + 1];
    }
    h_out[i * 16 + ln] = pack_bf16x2(tanhf(o0), tanhf(o1));
}

// ---------------------------------------------------------------------------
// Per-graph pooling (batch sorted) + linear head, reading packed bf16 h.
__global__ __launch_bounds__(256) void pool_kernel(const unsigned* __restrict__ hp,
                                                   const int* __restrict__ batch,
                                                   const float* __restrict__ Wout,
                                                   const float* __restrict__ bout,
                                                   float* __restrict__ out) {
    int b = blockIdx.x;
    int t = threadIdx.x;
    int lane_n = t >> 5;
    int j = t & 31;

    int lo = 0, hi = N_NODES;
    while (lo < hi) { int mid = (lo + hi) >> 1; if (batch[mid] < b) lo = mid + 1; else hi = mid; }
    int start = lo;
    hi = N_NODES;
    while (lo < hi) { int mid = (lo + hi) >> 1; if (batch[mid] < b + 1) lo = mid + 1; else hi = mid; }
    int end = lo;

    float vmax = -INFINITY, vsum = 0.f;
    for (int i = start + lane_n; i < end; i += 8) {
        unsigned q = hp[i * 16 + (j >> 1)];
        float v = (j & 1) ? bf_hi(q) : bf_lo(q);
        vmax = fmaxf(vmax, v);
        vsum += v;
    }

    __shared__ float smax[8][32];
    __shared__ float ssum[8][32];
    __shared__ float pool96[96];
    smax[lane_n][j] = vmax;
    ssum[lane_n][j] = vsum;
    __syncthreads();

    if (t < 32) {
        float m = smax[0][t], s = ssum[0][t];
#pragma unroll
        for (int n = 1; n < 8; ++n) { m = fmaxf(m, smax[n][t]); s += ssum[n][t]; }
        int cnt = end - start;
        float mean = s / fmaxf((float)cnt, 1.0f);
        pool96[t]      = m;
        pool96[32 + t] = mean;
        pool96[64 + t] = s;
    }
    __syncthreads();

    if (t < 96) out[B_GRAPHS + b * 96 + t] = pool96[t];

    __shared__ float dotbuf[96];
    if (t < 96) dotbuf[t] = pool96[t] * Wout[t];
    __syncthreads();
    if (t == 0) {
        float acc = 0.f;
#pragma unroll
        for (int k = 0; k < 96; ++k) acc += dotbuf[k];
        out[b] = acc + bout[0];
    }
}

// ---------------------------------------------------------------------------
extern "C" void kernel_launch(void* const* d_in, const int* in_sizes, int n_in,
                              void* d_out, int out_size, void* d_ws, size_t ws_size,
                              hipStream_t stream) {
    const float* x     = (const float*)d_in[0];
    const int*   ei    = (const int*)  d_in[1];   // src = ei[0:E], dst = ei[E:2E]
    const int*   batch = (const int*)  d_in[2];
    const float* W0    = (const float*)d_in[3];
    const float* b0    = (const float*)d_in[4];
    const float* W1    = (const float*)d_in[5];
    const float* b1    = (const float*)d_in[6];
    const float* W2    = (const float*)d_in[7];
    const float* b2    = (const float*)d_in[8];
    const float* W3    = (const float*)d_in[9];
    const float* b3    = (const float*)d_in[10];
    const float* Wout  = (const float*)d_in[11];
    const float* bout  = (const float*)d_in[12];
    float* out = (float*)d_out;

    char* p = (char*)d_ws;
    float*    dinv       = (float*)p;    p += (size_t)N_NODES * 4;
    unsigned* hA         = (unsigned*)p; p += (size_t)N_NODES * 16 * 4;
    unsigned* rec        = (unsigned*)p; p += (size_t)NBUCKET * CAPB * 4;     // reused as hB
    int2*     csr        = (int2*)p;     p += (size_t)TPAD * 8;
    int2*     row_meta   = (int2*)p;     p += (size_t)NBUCKET * BSIZE * 8;
    int*      perm       = (int*)p;      p += (size_t)NBUCKET * BSIZE * 4;
    int*      bucket_cur = (int*)p;      p += NBUCKET * 4;
    unsigned* hB = rec;   // alias: rec dead once passC completes

    // ---- edge build: fixed-stride buckets -> ranked per-bucket CSR ----
    init_cur_kernel<<<(NBUCKET + 255) / 256, 256, 0, stream>>>(bucket_cur);
    passB_kernel<<<NCHUNK, 256, 0, stream>>>(ei, bucket_cur, rec);
    dinv_kernel<<<NBUCKET, 256, 0, stream>>>(rec, bucket_cur, dinv);
    passC_kernel<<<NBUCKET, 256, 0, stream>>>(rec, bucket_cur, dinv,
                                              row_meta, perm, csr);

    // ---- 4 GCN layers (rank-scheduled gather) ----
    layer_kernel<F_IN, false><<<LAYER_BLOCKS, 256, 0, stream>>>(
        x,  row_meta, perm, (const v4i*)csr, dinv, W0, b0, hA);
    layer_kernel<H_DIM, true><<<LAYER_BLOCKS, 256, 0, stream>>>(
        hA, row_meta, perm, (const v4i*)csr, dinv, W1, b1, hB);
    layer_kernel<H_DIM, true><<<LAYER_BLOCKS, 256, 0, stream>>>(
        hB, row_meta, perm, (const v4i*)csr, dinv, W2, b2, hA);
    layer_kernel<H_DIM, true><<<LAYER_BLOCKS, 256, 0, stream>>>(
        hA, row_meta, perm, (const v4i*)csr, dinv, W3, b3, hB);

    pool_kernel<<<B_GRAPHS, 256, 0, stream>>>(hB, batch, Wout, bout, out);
}

// Round 11
// 275.011 us; speedup vs baseline: 1.1471x; 1.1471x over previous
//
#include <hip/hip_runtime.h>
#include <math.h>

#define N_NODES 100000
#define N_EDGES 1600000
#define F_IN    16
#define H_DIM   32
#define B_GRAPHS 256

#define BSHIFT  7
#define BSIZE   128                                   // nodes per bucket
#define NBUCKET ((N_NODES + BSIZE - 1) / BSIZE)       // 782
#define EPB     2048                                  // edges per chunk block (was 8192: grid-starved)
#define NCHUNK  ((N_EDGES + EPB - 1) / EPB)           // 782
#define CAPB    2560                                  // fixed bucket stride (mean 2048, +11 sigma)
#define CSTRIDE 2944                                  // csr entries reserved per bucket (2560+384)
#define TPAD    (NBUCKET * CSTRIDE)
#define NPB     16                                    // nodes per layer block
#define LAYER_BLOCKS (N_NODES / NPB)                  // 6250

// ---------------------------------------------------------------------------
__device__ inline float bf_lo(unsigned u) { return __uint_as_float(u << 16); }
__device__ inline float bf_hi(unsigned u) { return __uint_as_float(u & 0xffff0000u); }
__device__ inline unsigned pack_bf16x2(float a, float b) {
    unsigned ua = __float_as_uint(a), ub = __float_as_uint(b);
    ua += 0x7fffu + ((ua >> 16) & 1u);    // RNE
    ub += 0x7fffu + ((ub >> 16) & 1u);
    return (ua >> 16) | (ub & 0xffff0000u);
}

// ---------------------------------------------------------------------------
// bucket_cur[b] = b * CAPB  (fixed-stride bucket layout)
__global__ __launch_bounds__(256) void init_cur_kernel(int* __restrict__ bucket_cur) {
    int b = blockIdx.x * 256 + threadIdx.x;
    if (b < NBUCKET) bucket_cur[b] = b * CAPB;
}

// Pass B: per-block histogram -> claim per-bucket runs -> direct scattered
// writes (run-contiguous => low writeback amp). Record = src | dst_local<<20.
__global__ __launch_bounds__(256) void passB_kernel(const int* __restrict__ ei,
                                                    int* __restrict__ bucket_cur,
                                                    unsigned* __restrict__ rec_out) {
    __shared__ int hist[NBUCKET];
    __shared__ int gcur[NBUCKET];
    int t = threadIdx.x;
    for (int k = t; k < NBUCKET; k += 256) hist[k] = 0;
    __syncthreads();

    const int* dst = ei + N_EDGES;
    int base = blockIdx.x * EPB;
    int end  = base + EPB; if (end > N_EDGES) end = N_EDGES;

    for (int e = base + t; e < end; e += 256) atomicAdd(&hist[dst[e] >> BSHIFT], 1);
    __syncthreads();

    for (int k = t; k < NBUCKET; k += 256) {
        int h = hist[k];
        gcur[k] = h ? atomicAdd(&bucket_cur[k], h) : 0;
    }
    __syncthreads();

    for (int e = base + t; e < end; e += 256) {
        int d = dst[e], s = ei[e];
        int bk = d >> BSHIFT;
        int pos = atomicAdd(&gcur[bk], 1);
        rec_out[pos] = (unsigned)s | ((unsigned)(d & (BSIZE - 1)) << 20);
    }
}

// Per-bucket in-degree -> dinv
__global__ __launch_bounds__(256) void dinv_kernel(const unsigned* __restrict__ rec,
                                                   const int* __restrict__ bucket_end,
                                                   float* __restrict__ dinv) {
    __shared__ int cnt[BSIZE];
    int t = threadIdx.x, b = blockIdx.x;
    if (t < BSIZE) cnt[t] = 0;
    __syncthreads();
    int e1 = bucket_end[b];
    for (int e = b * CAPB + t; e < e1; e += 256) atomicAdd(&cnt[rec[e] >> 20], 1);
    __syncthreads();
    int nd = (b << BSHIFT) + t;
    if (t < BSIZE && nd < N_NODES) dinv[nd] = rsqrtf((float)cnt[t] + 1.0f);
}

// Pass C: per-bucket node sort into padded interleaved CSR: entry=(src,coef).
// Rows padded to multiples of 4; dummy entries use the row's OWN node as src
// (coef=0) so pad gathers are spread (no hot line). row_meta=(start,padded_len).
__global__ __launch_bounds__(256) void passC_kernel(const unsigned* __restrict__ rec,
                                                    const int* __restrict__ bucket_end,
                                                    const float* __restrict__ dinv,
                                                    int2* __restrict__ row_meta,
                                                    int2* __restrict__ csr) {
    __shared__ unsigned stage[CAPB];
    __shared__ int cnt[BSIZE];
    __shared__ int pds[BSIZE];
    __shared__ int cur[BSIZE];
    __shared__ float sdv[BSIZE];
    int t = threadIdx.x, b = blockIdx.x;
    int node0 = b << BSHIFT;
    int e0 = b * CAPB;
    int n = bucket_end[b] - e0;
    int pbase = b * CSTRIDE;              // 8-aligned (CSTRIDE % 8 == 0)
    if (t < BSIZE) {
        cnt[t] = 0;
        int nd = node0 + t;
        sdv[t] = (nd < N_NODES) ? dinv[nd] : 0.f;
    }
    __syncthreads();
    for (int k = t; k < n; k += 256) {
        unsigned r = rec[e0 + k];
        stage[k] = r;
        atomicAdd(&cnt[r >> 20], 1);
    }
    __syncthreads();
    // inclusive scan of pad-4 counts
    int pd = 0;
    if (t < BSIZE) { pd = (cnt[t] + 3) & ~3; pds[t] = pd; }
    __syncthreads();
    for (int off = 1; off < BSIZE; off <<= 1) {
        int v = (t < BSIZE && t >= off) ? pds[t - off] : 0;
        __syncthreads();
        if (t < BSIZE) pds[t] += v;
        __syncthreads();
    }
    if (t < BSIZE) {
        int startp = pbase + pds[t] - pd;
        cur[t] = startp;
        int nd = node0 + t;
        if (nd < N_NODES) {
            row_meta[nd] = make_int2(startp, pd);
            // dummy pad: own node as src, coef 0 (spread, no hot line)
            for (int k = startp + cnt[t]; k < startp + pd; ++k)
                csr[k] = make_int2(nd, 0);
        }
    }
    __syncthreads();
    for (int k = t; k < n; k += 256) {
        unsigned r = stage[k];
        int dl = r >> 20;
        int s  = r & 0xFFFFF;
        int pos = atomicAdd(&cur[dl], 1);
        csr[pos] = make_int2(s, __float_as_int(dinv[s] * sdv[dl]));
    }
}

// ---------------------------------------------------------------------------
// GCN layer: gather aggregation, 8-edge main chunks + uniform 4-edge tail,
// csr as int4 (2 edges/load); fused W + bias + tanh + bf16x2 pack.
template <int FIN, bool PACKED>
__global__ __launch_bounds__(256) void layer_kernel(
        const void* __restrict__ h_in_v,
        const int2* __restrict__ row_meta,
        const int4* __restrict__ csr4,     // 2 edges per int4
        const float* __restrict__ dinv,
        const float* __restrict__ W,       // [FIN][32]
        const float* __restrict__ bias,    // [32]
        unsigned* __restrict__ h_out) {
    constexpr int STR = FIN + 1;
    __shared__ float sW[FIN * H_DIM];
    __shared__ float sb[H_DIM];
    __shared__ float agg[NPB][STR];
    int t = threadIdx.x;
    for (int k = t; k < FIN * H_DIM; k += 256) sW[k] = W[k];
    if (t < H_DIM) sb[t] = bias[t];

    int nl = t >> 4, ln = t & 15;
    int i = blockIdx.x * NPB + nl;
    int2 m = row_meta[i];
    float di = dinv[i], di2 = di * di;
    int q    = m.x >> 1;                // int4 index of row start (16B-aligned)
    int qend = (m.x + m.y) >> 1;

    if (PACKED) {
        const unsigned* hp = (const unsigned*)h_in_v;
        unsigned u = hp[i * 16 + ln];
        float acc0 = bf_lo(u) * di2, acc1 = bf_hi(u) * di2;
        for (; q + 4 <= qend; q += 4) {
            int4 a = csr4[q], b = csr4[q + 1], c = csr4[q + 2], d = csr4[q + 3];
            unsigned v0 = hp[a.x * 16 + ln], v1 = hp[a.z * 16 + ln];
            unsigned v2 = hp[b.x * 16 + ln], v3 = hp[b.z * 16 + ln];
            unsigned v4 = hp[c.x * 16 + ln], v5 = hp[c.z * 16 + ln];
            unsigned v6 = hp[d.x * 16 + ln], v7 = hp[d.z * 16 + ln];
            float c0 = __int_as_float(a.y), c1 = __int_as_float(a.w);
            float c2 = __int_as_float(b.y), c3 = __int_as_float(b.w);
            float c4 = __int_as_float(c.y), c5 = __int_as_float(c.w);
            float c6 = __int_as_float(d.y), c7 = __int_as_float(d.w);
            acc0 += bf_lo(v0) * c0 + bf_lo(v1) * c1 + bf_lo(v2) * c2 + bf_lo(v3) * c3
                  + bf_lo(v4) * c4 + bf_lo(v5) * c5 + bf_lo(v6) * c6 + bf_lo(v7) * c7;
            acc1 += bf_hi(v0) * c0 + bf_hi(v1) * c1 + bf_hi(v2) * c2 + bf_hi(v3) * c3
                  + bf_hi(v4) * c4 + bf_hi(v5) * c5 + bf_hi(v6) * c6 + bf_hi(v7) * c7;
        }
        if (q < qend) {                  // exactly 2 int4s (4 edges)
            int4 a = csr4[q], b = csr4[q + 1];
            unsigned v0 = hp[a.x * 16 + ln], v1 = hp[a.z * 16 + ln];
            unsigned v2 = hp[b.x * 16 + ln], v3 = hp[b.z * 16 + ln];
            float c0 = __int_as_float(a.y), c1 = __int_as_float(a.w);
            float c2 = __int_as_float(b.y), c3 = __int_as_float(b.w);
            acc0 += bf_lo(v0) * c0 + bf_lo(v1) * c1 + bf_lo(v2) * c2 + bf_lo(v3) * c3;
            acc1 += bf_hi(v0) * c0 + bf_hi(v1) * c1 + bf_hi(v2) * c2 + bf_hi(v3) * c3;
        }
        agg[nl][2 * ln]     = acc0;
        agg[nl][2 * ln + 1] = acc1;
    } else {
        const float* xf = (const float*)h_in_v;
        float acc = xf[i * F_IN + ln] * di2;
        for (; q + 4 <= qend; q += 4) {
            int4 a = csr4[q], b = csr4[q + 1], c = csr4[q + 2], d = csr4[q + 3];
            float v0 = xf[a.x * F_IN + ln], v1 = xf[a.z * F_IN + ln];
            float v2 = xf[b.x * F_IN + ln], v3 = xf[b.z * F_IN + ln];
            float v4 = xf[c.x * F_IN + ln], v5 = xf[c.z * F_IN + ln];
            float v6 = xf[d.x * F_IN + ln], v7 = xf[d.z * F_IN + ln];
            acc += v0 * __int_as_float(a.y) + v1 * __int_as_float(a.w)
                 + v2 * __int_as_float(b.y) + v3 * __int_as_float(b.w)
                 + v4 * __int_as_float(c.y) + v5 * __int_as_float(c.w)
                 + v6 * __int_as_float(d.y) + v7 * __int_as_float(d.w);
        }
        if (q < qend) {
            int4 a = csr4[q], b = csr4[q + 1];
            float v0 = xf[a.x * F_IN + ln], v1 = xf[a.z * F_IN + ln];
            float v2 = xf[b.x * F_IN + ln], v3 = xf[b.z * F_IN + ln];
            acc += v0 * __int_as_float(a.y) + v1 * __int_as_float(a.w)
                 + v2 * __int_as_float(b.y) + v3 * __int_as_float(b.w);
        }
        agg[nl][ln] = acc;
    }
    __syncthreads();

    // transform + bias + tanh + pack  (16 nodes x 16 feat-pairs)
    int j0 = 2 * ln;
    float o0 = sb[j0], o1 = sb[j0 + 1];
    const float* arow = &agg[nl][0];
#pragma unroll
    for (int k = 0; k < FIN; ++k) {
        float a = arow[k];
        o0 += a * sW[k * H_DIM + j0];
        o1 += a * sW[k * H_DIM + j0 + 1];
    }
    h_out[i * 16 + ln] = pack_bf16x2(tanhf(o0), tanhf(o1));
}

// ---------------------------------------------------------------------------
// Per-graph pooling (batch sorted) + linear head, reading packed bf16 h.
__global__ __launch_bounds__(256) void pool_kernel(const unsigned* __restrict__ hp,
                                                   const int* __restrict__ batch,
                                                   const float* __restrict__ Wout,
                                                   const float* __restrict__ bout,
                                                   float* __restrict__ out) {
    int b = blockIdx.x;
    int t = threadIdx.x;
    int lane_n = t >> 5;
    int j = t & 31;

    int lo = 0, hi = N_NODES;
    while (lo < hi) { int mid = (lo + hi) >> 1; if (batch[mid] < b) lo = mid + 1; else hi = mid; }
    int start = lo;
    hi = N_NODES;
    while (lo < hi) { int mid = (lo + hi) >> 1; if (batch[mid] < b + 1) lo = mid + 1; else hi = mid; }
    int end = lo;

    float vmax = -INFINITY, vsum = 0.f;
    for (int i = start + lane_n; i < end; i += 8) {
        unsigned q = hp[i * 16 + (j >> 1)];
        float v = (j & 1) ? bf_hi(q) : bf_lo(q);
        vmax = fmaxf(vmax, v);
        vsum += v;
    }

    __shared__ float smax[8][32];
    __shared__ float ssum[8][32];
    __shared__ float pool96[96];
    smax[lane_n][j] = vmax;
    ssum[lane_n][j] = vsum;
    __syncthreads();

    if (t < 32) {
        float m = smax[0][t], s = ssum[0][t];
#pragma unroll
        for (int n = 1; n < 8; ++n) { m = fmaxf(m, smax[n][t]); s += ssum[n][t]; }
        int cnt = end - start;
        float mean = s / fmaxf((float)cnt, 1.0f);
        pool96[t]      = m;
        pool96[32 + t] = mean;
        pool96[64 + t] = s;
    }
    __syncthreads();

    if (t < 96) out[B_GRAPHS + b * 96 + t] = pool96[t];

    __shared__ float dotbuf[96];
    if (t < 96) dotbuf[t] = pool96[t] * Wout[t];
    __syncthreads();
    if (t == 0) {
        float acc = 0.f;
#pragma unroll
        for (int k = 0; k < 96; ++k) acc += dotbuf[k];
        out[b] = acc + bout[0];
    }
}

// ---------------------------------------------------------------------------
extern "C" void kernel_launch(void* const* d_in, const int* in_sizes, int n_in,
                              void* d_out, int out_size, void* d_ws, size_t ws_size,
                              hipStream_t stream) {
    const float* x     = (const float*)d_in[0];
    const int*   ei    = (const int*)  d_in[1];   // src = ei[0:E], dst = ei[E:2E]
    const int*   batch = (const int*)  d_in[2];
    const float* W0    = (const float*)d_in[3];
    const float* b0    = (const float*)d_in[4];
    const float* W1    = (const float*)d_in[5];
    const float* b1    = (const float*)d_in[6];
    const float* W2    = (const float*)d_in[7];
    const float* b2    = (const float*)d_in[8];
    const float* W3    = (const float*)d_in[9];
    const float* b3    = (const float*)d_in[10];
    const float* Wout  = (const float*)d_in[11];
    const float* bout  = (const float*)d_in[12];
    float* out = (float*)d_out;

    char* p = (char*)d_ws;
    float*    dinv       = (float*)p;    p += (size_t)N_NODES * 4;            // 16B-mult
    unsigned* hA         = (unsigned*)p; p += (size_t)N_NODES * 16 * 4;
    unsigned* rec        = (unsigned*)p; p += (size_t)NBUCKET * CAPB * 4;     // 8 MB, reused as hB
    int2*     csr        = (int2*)p;     p += (size_t)TPAD * 8;               // 18.4 MB
    int2*     row_meta   = (int2*)p;     p += (size_t)N_NODES * 8;
    int*      bucket_cur = (int*)p;      p += NBUCKET * 4;
    unsigned* hB = rec;   // alias: rec dead once passC completes

    // ---- edge build: fixed-stride buckets -> per-bucket node sort -> CSR ----
    init_cur_kernel<<<(NBUCKET + 255) / 256, 256, 0, stream>>>(bucket_cur);
    passB_kernel<<<NCHUNK, 256, 0, stream>>>(ei, bucket_cur, rec);
    dinv_kernel<<<NBUCKET, 256, 0, stream>>>(rec, bucket_cur, dinv);
    passC_kernel<<<NBUCKET, 256, 0, stream>>>(rec, bucket_cur, dinv, row_meta, csr);

    // ---- 4 GCN layers (gather, no atomics, int4 csr) ----
    layer_kernel<F_IN, false><<<LAYER_BLOCKS, 256, 0, stream>>>(
        x,  row_meta, (const int4*)csr, dinv, W0, b0, hA);
    layer_kernel<H_DIM, true><<<LAYER_BLOCKS, 256, 0, stream>>>(
        hA, row_meta, (const int4*)csr, dinv, W1, b1, hB);
    layer_kernel<H_DIM, true><<<LAYER_BLOCKS, 256, 0, stream>>>(
        hB, row_meta, (const int4*)csr, dinv, W2, b2, hA);
    layer_kernel<H_DIM, true><<<LAYER_BLOCKS, 256, 0, stream>>>(
        hA, row_meta, (const int4*)csr, dinv, W3, b3, hB);

    pool_kernel<<<B_GRAPHS, 256, 0, stream>>>(hB, batch, Wout, bout, out);
}

// Round 12
// 259.473 us; speedup vs baseline: 1.2158x; 1.0599x over previous
//
#include <hip/hip_runtime.h>
#include <math.h>

#define N_NODES 100000
#define N_EDGES 1600000
#define F_IN    16
#define H_DIM   32
#define B_GRAPHS 256

#define BSHIFT  7
#define BSIZE   128                                   // nodes per bucket
#define NBUCKET ((N_NODES + BSIZE - 1) / BSIZE)       // 782
#define EPB     8192                                  // edges per chunk block
#define NCHUNK  ((N_EDGES + EPB - 1) / EPB)           // 196
#define CAPB    2560                                  // fixed bucket stride (mean 2048, +11 sigma)
#define CSTRIDE 2944                                  // csr entries reserved per bucket (2560+384)
#define TPAD    (NBUCKET * CSTRIDE)
#define CURSTR  16                                    // bucket_cur stride: 1 counter / 64B line
#define NPB     16                                    // nodes per layer block
#define LAYER_BLOCKS (N_NODES / NPB)                  // 6250

// ---------------------------------------------------------------------------
__device__ inline float bf_lo(unsigned u) { return __uint_as_float(u << 16); }
__device__ inline float bf_hi(unsigned u) { return __uint_as_float(u & 0xffff0000u); }
__device__ inline unsigned pack_bf16x2(float a, float b) {
    unsigned ua = __float_as_uint(a), ub = __float_as_uint(b);
    ua += 0x7fffu + ((ua >> 16) & 1u);    // RNE
    ub += 0x7fffu + ((ub >> 16) & 1u);
    return (ua >> 16) | (ub & 0xffff0000u);
}

// ---------------------------------------------------------------------------
// bucket_cur[b*CURSTR] = b * CAPB  (line-isolated counters, no atomic line contention)
__global__ __launch_bounds__(256) void init_cur_kernel(int* __restrict__ bucket_cur) {
    int b = blockIdx.x * 256 + threadIdx.x;
    if (b < NBUCKET) bucket_cur[b * CURSTR] = b * CAPB;
}

// Pass B: per-block histogram -> claim per-bucket runs -> direct scattered
// writes. 1024-thread blocks (16 waves) hide store latency; line-isolated
// claim counters. Record = src | dst_local<<20.
__global__ __launch_bounds__(1024) void passB_kernel(const int* __restrict__ ei,
                                                     int* __restrict__ bucket_cur,
                                                     unsigned* __restrict__ rec_out) {
    __shared__ int hist[NBUCKET];
    __shared__ int gcur[NBUCKET];
    int t = threadIdx.x;
    for (int k = t; k < NBUCKET; k += 1024) hist[k] = 0;
    __syncthreads();

    const int* dst = ei + N_EDGES;
    int base = blockIdx.x * EPB;
    int end  = base + EPB; if (end > N_EDGES) end = N_EDGES;

    for (int e = base + t; e < end; e += 1024) atomicAdd(&hist[dst[e] >> BSHIFT], 1);
    __syncthreads();

    for (int k = t; k < NBUCKET; k += 1024) {
        int h = hist[k];
        gcur[k] = h ? atomicAdd(&bucket_cur[k * CURSTR], h) : 0;
    }
    __syncthreads();

    for (int e = base + t; e < end; e += 1024) {
        int d = dst[e], s = ei[e];
        int bk = d >> BSHIFT;
        int pos = atomicAdd(&gcur[bk], 1);
        rec_out[pos] = (unsigned)s | ((unsigned)(d & (BSIZE - 1)) << 20);
    }
}

// Per-bucket in-degree -> dinv
__global__ __launch_bounds__(256) void dinv_kernel(const unsigned* __restrict__ rec,
                                                   const int* __restrict__ bucket_cur,
                                                   float* __restrict__ dinv) {
    __shared__ int cnt[BSIZE];
    int t = threadIdx.x, b = blockIdx.x;
    if (t < BSIZE) cnt[t] = 0;
    __syncthreads();
    int e1 = bucket_cur[b * CURSTR];
    for (int e = b * CAPB + t; e < e1; e += 256) atomicAdd(&cnt[rec[e] >> 20], 1);
    __syncthreads();
    int nd = (b << BSHIFT) + t;
    if (t < BSIZE && nd < N_NODES) dinv[nd] = rsqrtf((float)cnt[t] + 1.0f);
}

// Pass C: per-bucket node sort into padded interleaved CSR: entry=(src,coef).
// Rows padded to multiples of 4; dummy entries use the row's OWN node as src
// (coef=0) so pad gathers are spread. row_meta=(start,padded_len).
__global__ __launch_bounds__(256) void passC_kernel(const unsigned* __restrict__ rec,
                                                    const int* __restrict__ bucket_cur,
                                                    const float* __restrict__ dinv,
                                                    int2* __restrict__ row_meta,
                                                    int2* __restrict__ csr) {
    __shared__ unsigned stage[CAPB];
    __shared__ int cnt[BSIZE];
    __shared__ int pds[BSIZE];
    __shared__ int cur[BSIZE];
    __shared__ float sdv[BSIZE];
    int t = threadIdx.x, b = blockIdx.x;
    int node0 = b << BSHIFT;
    int e0 = b * CAPB;
    int n = bucket_cur[b * CURSTR] - e0;
    int pbase = b * CSTRIDE;              // 8-aligned (CSTRIDE % 8 == 0)
    if (t < BSIZE) {
        cnt[t] = 0;
        int nd = node0 + t;
        sdv[t] = (nd < N_NODES) ? dinv[nd] : 0.f;
    }
    __syncthreads();
    for (int k = t; k < n; k += 256) {
        unsigned r = rec[e0 + k];
        stage[k] = r;
        atomicAdd(&cnt[r >> 20], 1);
    }
    __syncthreads();
    // inclusive scan of pad-4 counts
    int pd = 0;
    if (t < BSIZE) { pd = (cnt[t] + 3) & ~3; pds[t] = pd; }
    __syncthreads();
    for (int off = 1; off < BSIZE; off <<= 1) {
        int v = (t < BSIZE && t >= off) ? pds[t - off] : 0;
        __syncthreads();
        if (t < BSIZE) pds[t] += v;
        __syncthreads();
    }
    if (t < BSIZE) {
        int startp = pbase + pds[t] - pd;
        cur[t] = startp;
        int nd = node0 + t;
        if (nd < N_NODES) {
            row_meta[nd] = make_int2(startp, pd);
            for (int k = startp + cnt[t]; k < startp + pd; ++k)
                csr[k] = make_int2(nd, 0);   // dummy: own node, coef 0
        }
    }
    __syncthreads();
    for (int k = t; k < n; k += 256) {
        unsigned r = stage[k];
        int dl = r >> 20;
        int s  = r & 0xFFFFF;
        int pos = atomicAdd(&cur[dl], 1);
        csr[pos] = make_int2(s, __float_as_int(dinv[s] * sdv[dl]));
    }
}

// ---------------------------------------------------------------------------
// GCN layer: gather aggregation, 16-edge main chunks (+8/+4 tails) for deep
// MLP; csr as int4 (2 edges/load); fused W + bias + tanh + bf16x2 pack.
template <int FIN, bool PACKED>
__global__ __launch_bounds__(256) void layer_kernel(
        const void* __restrict__ h_in_v,
        const int2* __restrict__ row_meta,
        const int4* __restrict__ csr4,     // 2 edges per int4
        const float* __restrict__ dinv,
        const float* __restrict__ W,       // [FIN][32]
        const float* __restrict__ bias,    // [32]
        unsigned* __restrict__ h_out) {
    constexpr int STR = FIN + 1;
    __shared__ float sW[FIN * H_DIM];
    __shared__ float sb[H_DIM];
    __shared__ float agg[NPB][STR];
    int t = threadIdx.x;
    for (int k = t; k < FIN * H_DIM; k += 256) sW[k] = W[k];
    if (t < H_DIM) sb[t] = bias[t];

    int nl = t >> 4, ln = t & 15;
    int i = blockIdx.x * NPB + nl;
    int2 m = row_meta[i];
    float di = dinv[i], di2 = di * di;
    int q    = m.x >> 1;                // int4 index of row start (16B-aligned)
    int qend = (m.x + m.y) >> 1;

    if (PACKED) {
        const unsigned* hp = (const unsigned*)h_in_v;
        unsigned u = hp[i * 16 + ln];
        float acc0 = bf_lo(u) * di2, acc1 = bf_hi(u) * di2;
        for (; q + 8 <= qend; q += 8) {     // 16 edges in flight
            int4 ca[8];
#pragma unroll
            for (int k = 0; k < 8; ++k) ca[k] = csr4[q + k];
            unsigned v[16];
#pragma unroll
            for (int k = 0; k < 8; ++k) {
                v[2 * k]     = hp[ca[k].x * 16 + ln];
                v[2 * k + 1] = hp[ca[k].z * 16 + ln];
            }
#pragma unroll
            for (int k = 0; k < 8; ++k) {
                float c0 = __int_as_float(ca[k].y), c1 = __int_as_float(ca[k].w);
                acc0 += bf_lo(v[2 * k]) * c0 + bf_lo(v[2 * k + 1]) * c1;
                acc1 += bf_hi(v[2 * k]) * c0 + bf_hi(v[2 * k + 1]) * c1;
            }
        }
        if (q + 4 <= qend) {                // 8-edge tail
            int4 ca[4];
#pragma unroll
            for (int k = 0; k < 4; ++k) ca[k] = csr4[q + k];
#pragma unroll
            for (int k = 0; k < 4; ++k) {
                unsigned v0 = hp[ca[k].x * 16 + ln], v1 = hp[ca[k].z * 16 + ln];
                float c0 = __int_as_float(ca[k].y), c1 = __int_as_float(ca[k].w);
                acc0 += bf_lo(v0) * c0 + bf_lo(v1) * c1;
                acc1 += bf_hi(v0) * c0 + bf_hi(v1) * c1;
            }
            q += 4;
        }
        if (q < qend) {                     // 4-edge tail (2 int4s)
            int4 a = csr4[q], b = csr4[q + 1];
            unsigned v0 = hp[a.x * 16 + ln], v1 = hp[a.z * 16 + ln];
            unsigned v2 = hp[b.x * 16 + ln], v3 = hp[b.z * 16 + ln];
            float c0 = __int_as_float(a.y), c1 = __int_as_float(a.w);
            float c2 = __int_as_float(b.y), c3 = __int_as_float(b.w);
            acc0 += bf_lo(v0) * c0 + bf_lo(v1) * c1 + bf_lo(v2) * c2 + bf_lo(v3) * c3;
            acc1 += bf_hi(v0) * c0 + bf_hi(v1) * c1 + bf_hi(v2) * c2 + bf_hi(v3) * c3;
        }
        agg[nl][2 * ln]     = acc0;
        agg[nl][2 * ln + 1] = acc1;
    } else {
        const float* xf = (const float*)h_in_v;
        float acc = xf[i * F_IN + ln] * di2;
        for (; q + 8 <= qend; q += 8) {
            int4 ca[8];
#pragma unroll
            for (int k = 0; k < 8; ++k) ca[k] = csr4[q + k];
            float v[16];
#pragma unroll
            for (int k = 0; k < 8; ++k) {
                v[2 * k]     = xf[ca[k].x * F_IN + ln];
                v[2 * k + 1] = xf[ca[k].z * F_IN + ln];
            }
#pragma unroll
            for (int k = 0; k < 8; ++k)
                acc += v[2 * k] * __int_as_float(ca[k].y)
                     + v[2 * k + 1] * __int_as_float(ca[k].w);
        }
        if (q + 4 <= qend) {
            int4 ca[4];
#pragma unroll
            for (int k = 0; k < 4; ++k) ca[k] = csr4[q + k];
#pragma unroll
            for (int k = 0; k < 4; ++k)
                acc += xf[ca[k].x * F_IN + ln] * __int_as_float(ca[k].y)
                     + xf[ca[k].z * F_IN + ln] * __int_as_float(ca[k].w);
            q += 4;
        }
        if (q < qend) {
            int4 a = csr4[q], b = csr4[q + 1];
            acc += xf[a.x * F_IN + ln] * __int_as_float(a.y)
                 + xf[a.z * F_IN + ln] * __int_as_float(a.w)
                 + xf[b.x * F_IN + ln] * __int_as_float(b.y)
                 + xf[b.z * F_IN + ln] * __int_as_float(b.w);
        }
        agg[nl][ln] = acc;
    }
    __syncthreads();

    // transform + bias + tanh + pack  (16 nodes x 16 feat-pairs)
    int j0 = 2 * ln;
    float o0 = sb[j0], o1 = sb[j0 + 1];
    const float* arow = &agg[nl][0];
#pragma unroll
    for (int k = 0; k < FIN; ++k) {
        float a = arow[k];
        o0 += a * sW[k * H_DIM + j0];
        o1 += a * sW[k * H_DIM + j0 + 1];
    }
    h_out[i * 16 + ln] = pack_bf16x2(tanhf(o0), tanhf(o1));
}

// ---------------------------------------------------------------------------
// Per-graph pooling (batch sorted) + linear head, reading packed bf16 h.
__global__ __launch_bounds__(256) void pool_kernel(const unsigned* __restrict__ hp,
                                                   const int* __restrict__ batch,
                                                   const float* __restrict__ Wout,
                                                   const float* __restrict__ bout,
                                                   float* __restrict__ out) {
    int b = blockIdx.x;
    int t = threadIdx.x;
    int lane_n = t >> 5;
    int j = t & 31;

    int lo = 0, hi = N_NODES;
    while (lo < hi) { int mid = (lo + hi) >> 1; if (batch[mid] < b) lo = mid + 1; else hi = mid; }
    int start = lo;
    hi = N_NODES;
    while (lo < hi) { int mid = (lo + hi) >> 1; if (batch[mid] < b + 1) lo = mid + 1; else hi = mid; }
    int end = lo;

    float vmax = -INFINITY, vsum = 0.f;
    for (int i = start + lane_n; i < end; i += 8) {
        unsigned q = hp[i * 16 + (j >> 1)];
        float v = (j & 1) ? bf_hi(q) : bf_lo(q);
        vmax = fmaxf(vmax, v);
        vsum += v;
    }

    __shared__ float smax[8][32];
    __shared__ float ssum[8][32];
    __shared__ float pool96[96];
    smax[lane_n][j] = vmax;
    ssum[lane_n][j] = vsum;
    __syncthreads();

    if (t < 32) {
        float m = smax[0][t], s = ssum[0][t];
#pragma unroll
        for (int n = 1; n < 8; ++n) { m = fmaxf(m, smax[n][t]); s += ssum[n][t]; }
        int cnt = end - start;
        float mean = s / fmaxf((float)cnt, 1.0f);
        pool96[t]      = m;
        pool96[32 + t] = mean;
        pool96[64 + t] = s;
    }
    __syncthreads();

    if (t < 96) out[B_GRAPHS + b * 96 + t] = pool96[t];

    __shared__ float dotbuf[96];
    if (t < 96) dotbuf[t] = pool96[t] * Wout[t];
    __syncthreads();
    if (t == 0) {
        float acc = 0.f;
#pragma unroll
        for (int k = 0; k < 96; ++k) acc += dotbuf[k];
        out[b] = acc + bout[0];
    }
}

// ---------------------------------------------------------------------------
extern "C" void kernel_launch(void* const* d_in, const int* in_sizes, int n_in,
                              void* d_out, int out_size, void* d_ws, size_t ws_size,
                              hipStream_t stream) {
    const float* x     = (const float*)d_in[0];
    const int*   ei    = (const int*)  d_in[1];   // src = ei[0:E], dst = ei[E:2E]
    const int*   batch = (const int*)  d_in[2];
    const float* W0    = (const float*)d_in[3];
    const float* b0    = (const float*)d_in[4];
    const float* W1    = (const float*)d_in[5];
    const float* b1    = (const float*)d_in[6];
    const float* W2    = (const float*)d_in[7];
    const float* b2    = (const float*)d_in[8];
    const float* W3    = (const float*)d_in[9];
    const float* b3    = (const float*)d_in[10];
    const float* Wout  = (const float*)d_in[11];
    const float* bout  = (const float*)d_in[12];
    float* out = (float*)d_out;

    char* p = (char*)d_ws;
    float*    dinv       = (float*)p;    p += (size_t)N_NODES * 4;            // 16B-mult
    unsigned* hA         = (unsigned*)p; p += (size_t)N_NODES * 16 * 4;
    unsigned* rec        = (unsigned*)p; p += (size_t)NBUCKET * CAPB * 4;     // 8 MB, reused as hB
    int2*     csr        = (int2*)p;     p += (size_t)TPAD * 8;               // 18.4 MB
    int2*     row_meta   = (int2*)p;     p += (size_t)N_NODES * 8;
    int*      bucket_cur = (int*)p;      p += (size_t)NBUCKET * CURSTR * 4;
    unsigned* hB = rec;   // alias: rec dead once passC completes

    // ---- edge build: fixed-stride buckets -> per-bucket node sort -> CSR ----
    init_cur_kernel<<<(NBUCKET + 255) / 256, 256, 0, stream>>>(bucket_cur);
    passB_kernel<<<NCHUNK, 1024, 0, stream>>>(ei, bucket_cur, rec);
    dinv_kernel<<<NBUCKET, 256, 0, stream>>>(rec, bucket_cur, dinv);
    passC_kernel<<<NBUCKET, 256, 0, stream>>>(rec, bucket_cur, dinv, row_meta, csr);

    // ---- 4 GCN layers (gather, no atomics, int4 csr, 16-deep MLP) ----
    layer_kernel<F_IN, false><<<LAYER_BLOCKS, 256, 0, stream>>>(
        x,  row_meta, (const int4*)csr, dinv, W0, b0, hA);
    layer_kernel<H_DIM, true><<<LAYER_BLOCKS, 256, 0, stream>>>(
        hA, row_meta, (const int4*)csr, dinv, W1, b1, hB);
    layer_kernel<H_DIM, true><<<LAYER_BLOCKS, 256, 0, stream>>>(
        hB, row_meta, (const int4*)csr, dinv, W2, b2, hA);
    layer_kernel<H_DIM, true><<<LAYER_BLOCKS, 256, 0, stream>>>(
        hA, row_meta, (const int4*)csr, dinv, W3, b3, hB);

    pool_kernel<<<B_GRAPHS, 256, 0, stream>>>(hB, batch, Wout, bout, out);
}